// Round 13
// baseline (204.633 us; speedup 1.0000x reference)
//
#include <hip/hip_runtime.h>
#include <math.h>

#define TOK   16384   // Bf * hw
#define HW    4096
#define C     128
#define D     64
#define HID   256

constexpr float LN_EPS = 1e-5f;
constexpr float EPS_R  = 1e-10f;
constexpr float QSCALE = 0.08838834764831845f; // 128^-0.5

typedef __attribute__((ext_vector_type(8))) short  bf16x8;
typedef __attribute__((ext_vector_type(4))) float  f32x4;
typedef __attribute__((ext_vector_type(2))) _Float16 half2v;
#define MFMA16(a, b, c) __builtin_amdgcn_mfma_f32_16x16x32_bf16((a), (b), (c), 0, 0, 0)

__device__ __forceinline__ float bflo(unsigned u) { return __uint_as_float(u << 16); }
__device__ __forceinline__ float bfhi(unsigned u) { return __uint_as_float(u & 0xffff0000u); }
__device__ __forceinline__ unsigned short f2bf(float f) {
  unsigned u = __float_as_uint(f);
  unsigned r = (u + 0x7fffu + ((u >> 16) & 1u)) >> 16;
  return (unsigned short)r;
}
__device__ __forceinline__ unsigned short f2h(float f) {
  _Float16 h = (_Float16)f;
  unsigned short r;
  __builtin_memcpy(&r, &h, 2);
  return r;
}
__device__ __forceinline__ float gelu_exact(float x) {
  return 0.5f * x * (1.0f + erff(x * 0.7071067811865476f));
}

union U4H { uint4 v; half2v h[4]; };
union U1H { unsigned v; half2v h; };

#if __has_builtin(__builtin_amdgcn_fdot2)
__device__ __forceinline__ float dot2h(half2v a, half2v b, float c) {
  return __builtin_amdgcn_fdot2(a, b, c, false);
}
#else
__device__ __forceinline__ float dot2h(half2v a, half2v b, float c) {
  return c + (float)a.x * (float)b.x + (float)a.y * (float)b.y;
}
#endif

// ---------------- K1: weight prep -> bf16 transposed ------------------------------
__global__ __launch_bounds__(256) void k_prep(const float* __restrict__ wq,
    const float* __restrict__ wk, const float* __restrict__ wv,
    const float* __restrict__ pw, const float* __restrict__ f1w,
    const float* __restrict__ f2w, unsigned short* __restrict__ wt) {
  int id = blockIdx.x * 256 + threadIdx.x;
  if (id < 16384) {
    int n = id >> 7, k = id & 127;
    wt[id] = f2bf(wq[k * 128 + n]);
  } else if (id < 32768) {
    int e = id - 16384; int n = e >> 7, k = e & 127;
    wt[id] = f2bf(wk[k * 128 + n]);
  } else if (id < 49152) {
    int e = id - 32768; int n = e >> 7, k = e & 127;
    wt[id] = f2bf(wv[k * 128 + n]);
  } else if (id < 65536) {
    int e = id - 49152; int n = e >> 7, k = e & 127;
    wt[id] = f2bf(pw[k * 128 + n]);
  } else if (id < 98304) {
    int e = id - 65536; int n = e >> 7, k = e & 127;
    wt[id] = f2bf(f1w[k * 256 + n]);
  } else {
    int e = id - 98304; int n = e >> 8, k = e & 255;
    wt[id] = f2bf(f2w[k * 128 + n]);
  }
}

// ---------------- K2: fused LN1 + QKV GEMM (16 tokens/block) ----------------------
__global__ __launch_bounds__(256) void k_ln1qkv(const float* __restrict__ feat,
    const float* __restrict__ g, const float* __restrict__ b,
    const unsigned short* __restrict__ wt,
    const float* __restrict__ bq, const float* __restrict__ bk,
    const float* __restrict__ bv, unsigned short* __restrict__ qh,
    unsigned short* __restrict__ ksw, unsigned short* __restrict__ vsw) {
  __shared__ float t16[16][C + 1];
  __shared__ unsigned short axn[16 * C];   // swizzled: byte ^= (row&15)<<4
  int tid = threadIdx.x;
  int lane = tid & 63, wave = tid >> 6;
  int t0 = blockIdx.x * 16;
  int nv = t0 >> 12, i0 = t0 & 4095;
  const float* fb = feat + (size_t)nv * C * HW;
  for (int e = tid; e < 16 * C; e += 256) {
    int ch = e >> 4, ii = e & 15;
    t16[ii][ch] = fb[(size_t)ch * HW + i0 + ii];
  }
  __syncthreads();
  for (int tkn = wave; tkn < 16; tkn += 4) {
    float a0 = t16[tkn][lane];
    float a1 = t16[tkn][lane + 64];
    float s = a0 + a1;
    for (int off = 32; off; off >>= 1) s += __shfl_xor(s, off, 64);
    float mean = s * (1.0f / 128.0f);
    float d0 = a0 - mean, d1 = a1 - mean;
    float v = d0 * d0 + d1 * d1;
    for (int off = 32; off; off >>= 1) v += __shfl_xor(v, off, 64);
    float rstd = rsqrtf(v * (1.0f / 128.0f) + LN_EPS);
    unsigned short x0 = f2bf(d0 * rstd * g[lane] + b[lane]);
    unsigned short x1 = f2bf(d1 * rstd * g[lane + 64] + b[lane + 64]);
    int b0 = (tkn * 256 + lane * 2) ^ ((tkn & 15) << 4);
    int b1 = (tkn * 256 + (lane + 64) * 2) ^ ((tkn & 15) << 4);
    *(unsigned short*)((char*)axn + b0) = x0;
    *(unsigned short*)((char*)axn + b1) = x1;
  }
  __syncthreads();
  // QKV: 24 col-tiles (3 mats x 8), 6 per wave
  int q4 = lane >> 4, m = lane & 15;
  bf16x8 a[4];
  #pragma unroll
  for (int ks = 0; ks < 4; ks++) {
    int boff = (m * 256 + ks * 64 + q4 * 16) ^ (m << 4);
    a[ks] = *(const bf16x8*)((char*)axn + boff);
  }
  int swbase = ((nv ^ 1) << 12) + i0;
  #pragma unroll
  for (int tt = 0; tt < 6; ++tt) {
    int gt = wave * 6 + tt;          // 0..23
    int mat = gt >> 3, ct = gt & 7;
    const unsigned short* bp = wt + mat * 16384 + (size_t)(ct * 16 + m) * C + q4 * 8;
    f32x4 acc = (f32x4){0.f, 0.f, 0.f, 0.f};
    #pragma unroll
    for (int ks = 0; ks < 4; ks++) {
      bf16x8 bfrag = *(const bf16x8*)(bp + ks * 32);
      acc = MFMA16(a[ks], bfrag, acc);
    }
    const float* B = (mat == 0) ? bq : ((mat == 1) ? bk : bv);
    float sc = (mat == 0) ? QSCALE : 1.0f;
    unsigned short* O = (mat == 0) ? qh : ((mat == 1) ? ksw : vsw);
    int base = (mat == 0) ? t0 : swbase;
    int col = ct * 16 + m;
    float bb = B[col];
    #pragma unroll
    for (int reg = 0; reg < 4; reg++) {
      int row = base + q4 * 4 + reg;
      O[(size_t)row * C + col] = f2h((acc[reg] + bb) * sc);
    }
  }
}

// ---------------- K3: fused gather-attention + proj + residual + LN2 + fc1 --------
// Occupancy-doubling experiment, resubmitted (R12 bench infra failed; kernel
// audit found no fault). 2048 blocks x 8 tokens, 2 tokens/wave in phase A
// (R11-verbatim body, tj<2). Grid now allows 8 blocks/CU -> 100% occ cap.
// Phases B/C keep the 16-row MFMA tile: rows 8-15 zero-filled, stores guarded by
// q4<2 (half-wave exec mask); feat reads for garbage rows clamped in-bounds.
__global__ __launch_bounds__(256, 3) void k_attn_proj_fc1(
    const unsigned short* __restrict__ qh, const unsigned short* __restrict__ ksw,
    const unsigned short* __restrict__ vsw, const int* __restrict__ widx,
    const float* __restrict__ dprob, const float* __restrict__ kpe,
    const float* __restrict__ vpe, const float* __restrict__ rpe,
    const unsigned short* __restrict__ wt, const float* __restrict__ pb,
    const float* __restrict__ feat, float* __restrict__ xio,
    const float* __restrict__ g2, const float* __restrict__ b2,
    const float* __restrict__ f1b, unsigned short* __restrict__ y) {
  // 16 rows x 128 ch bf16, XOR-swizzled: byte ^= (row&15)<<4. Rows 8-15 stay zero.
  __shared__ unsigned short axn[16 * C];
  __shared__ float ps1[4][16];
  __shared__ float ps2[4][16];
  int lane = threadIdx.x & 63;
  int wave = threadIdx.x >> 6;
  int bid = blockIdx.x;
  int n = (bid >> 1) & 3;                       // view pair -> XCD locality
  int within = ((bid >> 3) << 1) | (bid & 1);   // 0..511
  int T0 = n * HW + within * 8;
  const unsigned short* Kb = ksw + (size_t)n * HW * C;
  const unsigned short* Vb = vsw + (size_t)n * HW * C;
  int gg = lane >> 3, s = lane & 7;
  half2v ones = {(_Float16)1.0f, (_Float16)1.0f};

  // zero rows 8-15 of axn (2 KB) - swizzle permutes within a row, so linear ok
  if (threadIdx.x < 128)
    *(uint4*)((char*)axn + 2048 + threadIdx.x * 16) = make_uint4(0u, 0u, 0u, 0u);

  // ---- Phase A: attention, 2 tokens per wave (R11-verbatim body) ----
  for (int tj = 0; tj < 2; ++tj) {
    int token = T0 + wave * 2 + tj;
    int myidx = widx[(size_t)token * D + lane];
    float mydp = dprob[(size_t)token * D + lane];
    // Q segment (f16): channels [s*16, s*16+16) as 8 half2
    half2v qreg[8];
    {
      const unsigned short* qp = qh + (size_t)token * C + s * 16;
      U4H qa, qb2;
      qa.v = *(const uint4*)(qp);
      qb2.v = *(const uint4*)(qp + 8);
      #pragma unroll
      for (int i = 0; i < 4; i++) { qreg[i] = qa.h[i]; qreg[4 + i] = qb2.h[i]; }
    }
    // issue ALL 16 K-row loads
    int rowv[8];
    #pragma unroll
    for (int pass = 0; pass < 8; ++pass)
      rowv[pass] = __shfl(myidx, pass * 8 + gg, 64);
    uint4 ka[8], kb[8];
    #pragma unroll
    for (int pass = 0; pass < 8; ++pass) {
      const unsigned short* kr = Kb + (size_t)rowv[pass] * C + s * 16;
      ka[pass] = *(const uint4*)(kr);
      kb[pass] = *(const uint4*)(kr + 8);
    }
    // issue V batch 0 (32 rows) - in flight across QmK+softmax
    unsigned vv0[32];
    #pragma unroll
    for (int j = 0; j < 32; j++) {
      int row = __builtin_amdgcn_readlane(myidx, j);
      vv0[j] = *(const unsigned*)(Vb + (size_t)row * C + lane * 2);
    }
    // qpe (VALU, overlaps load latency)
    float qpe = 0.f;
    #pragma unroll
    for (int i = 0; i < 8; i++) qpe = dot2h(qreg[i], ones, qpe);
    qpe += __shfl_xor(qpe, 1, 64);
    qpe += __shfl_xor(qpe, 2, 64);
    qpe += __shfl_xor(qpe, 4, 64);
    // QmK (consumes ka/kb; V batch 0 still in flight)
    float mycost = 0.f;
    #pragma unroll
    for (int pass = 0; pass < 8; ++pass) {
      U4H ua, ub;
      ua.v = ka[pass]; ub.v = kb[pass];
      float p = 0.f;
      #pragma unroll
      for (int i = 0; i < 4; i++) p = dot2h(ua.h[i], qreg[i], p);
      #pragma unroll
      for (int i = 0; i < 4; i++) p = dot2h(ub.h[i], qreg[4 + i], p);
      p += __shfl_xor(p, 1, 64);
      p += __shfl_xor(p, 2, 64);
      p += __shfl_xor(p, 4, 64);
      float t = __shfl(p, (lane & 7) << 3, 64);
      if (pass == gg) mycost = t;
    }
    mycost += qpe * kpe[lane] + rpe[lane];
    // softmax + renorm (VALU/shfl only; V batch 0 still in flight)
    float mx = mycost;
    for (int off = 32; off; off >>= 1) mx = fmaxf(mx, __shfl_xor(mx, off, 64));
    float e = __expf(mycost - mx);
    float ssum = e;
    for (int off = 32; off; off >>= 1) ssum += __shfl_xor(ssum, off, 64);
    float attn = (e / ssum) * mydp;
    float s2 = attn;
    for (int off = 32; off; off >>= 1) s2 += __shfl_xor(s2, off, 64);
    attn = (attn + EPS_R) / (s2 + EPS_R);
    float vpt = attn * vpe[lane];
    for (int off = 32; off; off >>= 1) vpt += __shfl_xor(vpt, off, 64);
    // issue V batch 1 (32 rows), then consume batch 0, then batch 1
    float o0 = vpt, o1 = vpt;
    unsigned att_u = __float_as_uint(attn);
    unsigned vv1[32];
    #pragma unroll
    for (int j = 0; j < 32; j++) {
      int row = __builtin_amdgcn_readlane(myidx, 32 + j);
      vv1[j] = *(const unsigned*)(Vb + (size_t)row * C + lane * 2);
    }
    #pragma unroll
    for (int j = 0; j < 32; j++) {
      float a = __uint_as_float(__builtin_amdgcn_readlane(att_u, j));
      U1H h; h.v = vv0[j];
      o0 += a * (float)h.h.x;   // v_fma_mix_f32
      o1 += a * (float)h.h.y;
    }
    #pragma unroll
    for (int j = 0; j < 32; j++) {
      float a = __uint_as_float(__builtin_amdgcn_readlane(att_u, 32 + j));
      U1H h; h.v = vv1[j];
      o0 += a * (float)h.h.x;
      o1 += a * (float)h.h.y;
    }
    unsigned pk = (unsigned)f2bf(o0) | ((unsigned)f2bf(o1) << 16);
    int row = wave * 2 + tj;
    int boff = (row * 256 + lane * 4) ^ ((row & 15) << 4);
    *(unsigned*)((char*)axn + boff) = pk;
  }
  __syncthreads();

  // ---- Phase B: proj GEMM (8 valid tok x 32 cols per wave) + residual + LN2 ----
  int q4 = lane >> 4, m = lane & 15;
  bool vq = (q4 < 2);                      // rows 0..7 valid, 8..15 garbage
  bf16x8 a[4];
  #pragma unroll
  for (int ks = 0; ks < 4; ks++) {
    int boff = (m * 256 + ks * 64 + q4 * 16) ^ (m << 4);
    a[ks] = *(const bf16x8*)((char*)axn + boff);
  }
  const unsigned short* Wp = wt + 3 * 16384;  // pwT
  f32x4 acc[2];
  #pragma unroll
  for (int nt = 0; nt < 2; nt++) acc[nt] = (f32x4){0.f, 0.f, 0.f, 0.f};
  #pragma unroll
  for (int nt = 0; nt < 2; nt++) {
    int colt = wave * 32 + nt * 16;
    const unsigned short* bp = Wp + (size_t)(colt + m) * C + q4 * 8;
    #pragma unroll
    for (int ks = 0; ks < 4; ks++) {
      bf16x8 bfrag = *(const bf16x8*)(bp + ks * 32);
      acc[nt] = MFMA16(a[ks], bfrag, acc[nt]);
    }
  }
  // in-bounds base even for garbage rows (their values are discarded)
  int ibase = (T0 & 4095) + (vq ? q4 * 4 : 0);
  float s1[4] = {0.f, 0.f, 0.f, 0.f}, s2b[4] = {0.f, 0.f, 0.f, 0.f};
  #pragma unroll
  for (int nt = 0; nt < 2; nt++) {
    int col = wave * 32 + nt * 16 + m;
    float bb = pb[col];
    const float* fp = feat + ((size_t)n * C + col) * HW + ibase;
    #pragma unroll
    for (int reg = 0; reg < 4; reg++) {
      float v = acc[nt][reg] + bb + fp[reg];
      acc[nt][reg] = v;
      s1[reg] += v;
      s2b[reg] += v * v;
    }
  }
  #pragma unroll
  for (int reg = 0; reg < 4; reg++) {
    #pragma unroll
    for (int off = 1; off < 16; off <<= 1) {
      s1[reg] += __shfl_xor(s1[reg], off, 64);
      s2b[reg] += __shfl_xor(s2b[reg], off, 64);
    }
  }
  if (m == 0) {
    #pragma unroll
    for (int reg = 0; reg < 4; reg++) {
      ps1[wave][q4 * 4 + reg] = s1[reg];
      ps2[wave][q4 * 4 + reg] = s2b[reg];
    }
  }
  __syncthreads();
  float mean[4], rstd[4];
  #pragma unroll
  for (int reg = 0; reg < 4; reg++) {
    int row = q4 * 4 + reg;
    float t1 = ps1[0][row] + ps1[1][row] + ps1[2][row] + ps1[3][row];
    float t2 = ps2[0][row] + ps2[1][row] + ps2[2][row] + ps2[3][row];
    mean[reg] = t1 * (1.0f / 128.0f);
    float var = t2 * (1.0f / 128.0f) - mean[reg] * mean[reg];
    rstd[reg] = rsqrtf(var + LN_EPS);
  }
  if (vq) {
    #pragma unroll
    for (int nt = 0; nt < 2; nt++) {
      int col = wave * 32 + nt * 16 + m;
      float gc = g2[col], bc = b2[col];
      #pragma unroll
      for (int reg = 0; reg < 4; reg++) {
        int row = q4 * 4 + reg;
        float v = acc[nt][reg];
        xio[(size_t)(T0 + row) * C + col] = v;
        unsigned short xv = f2bf((v - mean[reg]) * rstd[reg] * gc + bc);
        int boff = (row * 256 + col * 2) ^ ((row & 15) << 4);
        *(unsigned short*)((char*)axn + boff) = xv;
      }
    }
  }
  __syncthreads();

  // ---- Phase C: fc1 GEMM (8 valid tok x 64 cols per wave) + GELU -> y ----
  bf16x8 af[4];
  #pragma unroll
  for (int ks = 0; ks < 4; ks++) {
    int boff = (m * 256 + ks * 64 + q4 * 16) ^ (m << 4);
    af[ks] = *(const bf16x8*)((char*)axn + boff);
  }
  const unsigned short* Wf = wt + 65536;  // f1wT [256][128]
  #pragma unroll
  for (int nt = 0; nt < 4; nt++) {
    int colt = wave * 64 + nt * 16;
    const unsigned short* bp = Wf + (size_t)(colt + m) * C + q4 * 8;
    f32x4 acc2 = (f32x4){0.f, 0.f, 0.f, 0.f};
    #pragma unroll
    for (int ks = 0; ks < 4; ks++) {
      bf16x8 bfrag = *(const bf16x8*)(bp + ks * 32);
      acc2 = MFMA16(af[ks], bfrag, acc2);
    }
    int col = colt + m;
    float bb = f1b[col];
    if (vq) {
      #pragma unroll
      for (int reg = 0; reg < 4; reg++) {
        int row = T0 + q4 * 4 + reg;
        y[(size_t)row * HID + col] = f2bf(gelu_exact(acc2[reg] + bb));
      }
    }
  }
}

// ---------------- K4: depthwise 5x5 conv + GELU; writes ysum = y + yc -------------
__global__ __launch_bounds__(256) void k_dwconv(const unsigned short* __restrict__ y,
    const float* __restrict__ w, const float* __restrict__ bias,
    unsigned short* __restrict__ ysum) {
  __shared__ float tile[8][401];   // [channel][spatial 20x20], odd stride
  __shared__ float wl[8][25];
  __shared__ float bl[8];
  __shared__ unsigned short outl[256][8];  // 16x16 spatial x 8 ch staging
  int bid = blockIdx.x;
  int tile_id = bid & 15;
  int cb = (bid >> 4) & 31;
  int n = bid >> 9;
  int ty = (tile_id >> 2) * 16, tx = (tile_id & 3) * 16;
  int ch0 = cb * 8;
  int tid = threadIdx.x;
  if (tid < 200) wl[tid / 25][tid % 25] = w[(size_t)(ch0 + tid / 25) * 25 + tid % 25];
  if (tid < 8) bl[tid] = bias[ch0 + tid];
  const unsigned short* yb = y + (size_t)n * HW * HID;
  for (int p = tid; p < 400; p += 256) {
    int py = p / 20, px = p % 20;
    int gy = ty + py - 2, gx = tx + px - 2;
    uint4 v = make_uint4(0u, 0u, 0u, 0u);
    if (gy >= 0 && gy < 64 && gx >= 0 && gx < 64)
      v = *(const uint4*)(yb + (size_t)(gy * 64 + gx) * HID + ch0);
    tile[0][p] = bflo(v.x); tile[1][p] = bfhi(v.x);
    tile[2][p] = bflo(v.y); tile[3][p] = bfhi(v.y);
    tile[4][p] = bflo(v.z); tile[5][p] = bfhi(v.z);
    tile[6][p] = bflo(v.w); tile[7][p] = bfhi(v.w);
  }
  __syncthreads();
  int cc = tid & 7;
  int xx = (tid >> 3) & 15;
  int yg = tid >> 7;
  float wreg[25];
  #pragma unroll
  for (int k = 0; k < 25; k++) wreg[k] = wl[cc][k];
  float bb = bl[cc];
  float win[12][5];
  #pragma unroll
  for (int r = 0; r < 12; r++)
    #pragma unroll
    for (int dx = 0; dx < 5; dx++)
      win[r][dx] = tile[cc][(yg * 8 + r) * 20 + xx + dx];
  #pragma unroll
  for (int j = 0; j < 8; ++j) {
    float acc = 0.f;
    #pragma unroll
    for (int dy = 0; dy < 5; ++dy)
      #pragma unroll
      for (int dx = 0; dx < 5; ++dx)
        acc += wreg[dy * 5 + dx] * win[j + dy][dx];
    float o = win[j + 2][2] + gelu_exact(acc + bb);
    int yy = yg * 8 + j;
    outl[yy * 16 + xx][cc] = f2bf(o);
  }
  __syncthreads();
  {
    int p = tid;
    int yy = p >> 4, xx2 = p & 15;
    uint4 val = *(const uint4*)outl[p];
    *(uint4*)(ysum + (size_t)(n * HW + (ty + yy) * 64 + tx + xx2) * HID + ch0) = val;
  }
}

// ---------------- K5: fc2 GEMM (MFMA, col-split x4) on ysum + residual ------------
__global__ __launch_bounds__(256) void k_fc2(const unsigned short* __restrict__ ysum,
    const unsigned short* __restrict__ wt, const float* __restrict__ f2b,
    const float* __restrict__ xio, float* __restrict__ outp) {
  int w = threadIdx.x >> 6, lane = threadIdx.x & 63;
  int q4 = lane >> 4, m = lane & 15;
  int t0 = blockIdx.x * 64 + w * 16;
  int quarter = blockIdx.y;
  const unsigned short* Wt = wt + 98304;  // f2wT [128][256]
  const unsigned short* ap = ysum + (size_t)(t0 + m) * HID + q4 * 8;
  bf16x8 a[8];
  #pragma unroll
  for (int ks = 0; ks < 8; ks++) a[ks] = *(const bf16x8*)(ap + ks * 32);
  f32x4 acc[2];
  #pragma unroll
  for (int nt = 0; nt < 2; nt++) acc[nt] = (f32x4){0.f, 0.f, 0.f, 0.f};
  #pragma unroll
  for (int nt = 0; nt < 2; nt++) {
    const unsigned short* bp = Wt + (size_t)(quarter * 32 + nt * 16 + m) * HID + q4 * 8;
    #pragma unroll
    for (int ks = 0; ks < 8; ks++) {
      bf16x8 bfrag = *(const bf16x8*)(bp + ks * 32);
      acc[nt] = MFMA16(a[ks], bfrag, acc[nt]);
    }
  }
  #pragma unroll
  for (int nt = 0; nt < 2; nt++) {
    int col = quarter * 32 + nt * 16 + m;
    float bb = f2b[col];
    #pragma unroll
    for (int reg = 0; reg < 4; reg++) {
      int row = t0 + q4 * 4 + reg;
      outp[(size_t)row * C + col] = acc[nt][reg] + bb + xio[(size_t)row * C + col];
    }
  }
}

extern "C" void kernel_launch(void* const* d_in, const int* in_sizes, int n_in,
                              void* d_out, int out_size, void* d_ws, size_t ws_size,
                              hipStream_t stream) {
  (void)in_sizes; (void)n_in; (void)out_size; (void)ws_size;
  const float* feat  = (const float*)d_in[0];
  const int*   widx  = (const int*)d_in[1];
  const float* dprob = (const float*)d_in[2];
  const float* ln1g  = (const float*)d_in[3];
  const float* ln1b  = (const float*)d_in[4];
  const float* wq    = (const float*)d_in[5];
  const float* bq    = (const float*)d_in[6];
  const float* wk    = (const float*)d_in[7];
  const float* bk    = (const float*)d_in[8];
  const float* wv    = (const float*)d_in[9];
  const float* bv    = (const float*)d_in[10];
  const float* kpe   = (const float*)d_in[11];
  const float* vpe   = (const float*)d_in[12];
  const float* rpe   = (const float*)d_in[13];
  const float* pw    = (const float*)d_in[14];
  const float* pb    = (const float*)d_in[15];
  const float* ln2g  = (const float*)d_in[16];
  const float* ln2b  = (const float*)d_in[17];
  const float* f1w   = (const float*)d_in[18];
  const float* f1b   = (const float*)d_in[19];
  const float* dww   = (const float*)d_in[20];
  const float* dwb   = (const float*)d_in[21];
  const float* f2w   = (const float*)d_in[22];
  const float* f2b   = (const float*)d_in[23];

  float* ws = (float*)d_ws;
  const size_t M2 = (size_t)TOK * C;  // 2,097,152 floats (8 MB)
  float* xio = ws;                                                   // fp32 residual stream
  unsigned short* qhb   = (unsigned short*)(ws + M2);                // f16 q (scaled)
  unsigned short* ksb   = (unsigned short*)(ws + 2 * M2);            // f16 K (swapped)
  unsigned short* vsb   = (unsigned short*)(ws + 2 * M2 + M2 / 2);   // f16 V (swapped)
  unsigned short* yb    = (unsigned short*)(ws + 3 * M2);            // bf16 fc1 out (2*M2 ush)
  unsigned short* ysumb = (unsigned short*)(ws + 4 * M2);            // bf16 y+yc (2*M2 ush)
  unsigned short* wtb   = (unsigned short*)(ws + 5 * M2);            // bf16 weights (131072 ush)

  k_prep   <<<512, 256, 0, stream>>>(wq, wk, wv, pw, f1w, f2w, wtb);
  k_ln1qkv <<<1024, 256, 0, stream>>>(feat, ln1g, ln1b, wtb, bq, bk, bv, qhb, ksb, vsb);
  k_attn_proj_fc1<<<2048, 256, 0, stream>>>(qhb, ksb, vsb, widx, dprob, kpe, vpe,
                                            rpe, wtb, pb, feat, xio, ln2g, ln2b,
                                            f1b, yb);
  k_dwconv <<<2048, 256, 0, stream>>>(yb, dww, dwb, ysumb);
  k_fc2    <<<dim3(TOK / 64, 4), 256, 0, stream>>>(ysumb, wtb, f2b, xio, (float*)d_out);
}

// Round 14
// 193.715 us; speedup vs baseline: 1.0564x; 1.0564x over previous
//
#include <hip/hip_runtime.h>
#include <math.h>

#define TOK   16384   // Bf * hw
#define HW    4096
#define C     128
#define D     64
#define HID   256

constexpr float LN_EPS = 1e-5f;
constexpr float EPS_R  = 1e-10f;
constexpr float QSCALE = 0.08838834764831845f; // 128^-0.5

typedef __attribute__((ext_vector_type(8))) short  bf16x8;
typedef __attribute__((ext_vector_type(4))) float  f32x4;
typedef __attribute__((ext_vector_type(2))) _Float16 half2v;
#define MFMA16(a, b, c) __builtin_amdgcn_mfma_f32_16x16x32_bf16((a), (b), (c), 0, 0, 0)

__device__ __forceinline__ float bflo(unsigned u) { return __uint_as_float(u << 16); }
__device__ __forceinline__ float bfhi(unsigned u) { return __uint_as_float(u & 0xffff0000u); }
__device__ __forceinline__ unsigned short f2bf(float f) {
  unsigned u = __float_as_uint(f);
  unsigned r = (u + 0x7fffu + ((u >> 16) & 1u)) >> 16;
  return (unsigned short)r;
}
__device__ __forceinline__ unsigned short f2h(float f) {
  _Float16 h = (_Float16)f;
  unsigned short r;
  __builtin_memcpy(&r, &h, 2);
  return r;
}
__device__ __forceinline__ float gelu_exact(float x) {
  return 0.5f * x * (1.0f + erff(x * 0.7071067811865476f));
}

union U4H { uint4 v; half2v h[4]; };
union U1H { unsigned v; half2v h; };

#if __has_builtin(__builtin_amdgcn_fdot2)
__device__ __forceinline__ float dot2h(half2v a, half2v b, float c) {
  return __builtin_amdgcn_fdot2(a, b, c, false);
}
#else
__device__ __forceinline__ float dot2h(half2v a, half2v b, float c) {
  return c + (float)a.x * (float)b.x + (float)a.y * (float)b.y;
}
#endif

// ---------------- K1: weight prep -> bf16 transposed ------------------------------
__global__ __launch_bounds__(256) void k_prep(const float* __restrict__ wq,
    const float* __restrict__ wk, const float* __restrict__ wv,
    const float* __restrict__ pw, const float* __restrict__ f1w,
    const float* __restrict__ f2w, unsigned short* __restrict__ wt) {
  int id = blockIdx.x * 256 + threadIdx.x;
  if (id < 16384) {
    int n = id >> 7, k = id & 127;
    wt[id] = f2bf(wq[k * 128 + n]);
  } else if (id < 32768) {
    int e = id - 16384; int n = e >> 7, k = e & 127;
    wt[id] = f2bf(wk[k * 128 + n]);
  } else if (id < 49152) {
    int e = id - 32768; int n = e >> 7, k = e & 127;
    wt[id] = f2bf(wv[k * 128 + n]);
  } else if (id < 65536) {
    int e = id - 49152; int n = e >> 7, k = e & 127;
    wt[id] = f2bf(pw[k * 128 + n]);
  } else if (id < 98304) {
    int e = id - 65536; int n = e >> 7, k = e & 127;
    wt[id] = f2bf(f1w[k * 256 + n]);
  } else {
    int e = id - 98304; int n = e >> 8, k = e & 255;
    wt[id] = f2bf(f2w[k * 128 + n]);
  }
}

// ---------------- K2: fused LN1 + QKV GEMM (16 tokens/block) ----------------------
__global__ __launch_bounds__(256) void k_ln1qkv(const float* __restrict__ feat,
    const float* __restrict__ g, const float* __restrict__ b,
    const unsigned short* __restrict__ wt,
    const float* __restrict__ bq, const float* __restrict__ bk,
    const float* __restrict__ bv, unsigned short* __restrict__ qh,
    unsigned short* __restrict__ ksw, unsigned short* __restrict__ vsw) {
  __shared__ float t16[16][C + 1];
  __shared__ unsigned short axn[16 * C];   // swizzled: byte ^= (row&15)<<4
  int tid = threadIdx.x;
  int lane = tid & 63, wave = tid >> 6;
  int t0 = blockIdx.x * 16;
  int nv = t0 >> 12, i0 = t0 & 4095;
  const float* fb = feat + (size_t)nv * C * HW;
  for (int e = tid; e < 16 * C; e += 256) {
    int ch = e >> 4, ii = e & 15;
    t16[ii][ch] = fb[(size_t)ch * HW + i0 + ii];
  }
  __syncthreads();
  for (int tkn = wave; tkn < 16; tkn += 4) {
    float a0 = t16[tkn][lane];
    float a1 = t16[tkn][lane + 64];
    float s = a0 + a1;
    for (int off = 32; off; off >>= 1) s += __shfl_xor(s, off, 64);
    float mean = s * (1.0f / 128.0f);
    float d0 = a0 - mean, d1 = a1 - mean;
    float v = d0 * d0 + d1 * d1;
    for (int off = 32; off; off >>= 1) v += __shfl_xor(v, off, 64);
    float rstd = rsqrtf(v * (1.0f / 128.0f) + LN_EPS);
    unsigned short x0 = f2bf(d0 * rstd * g[lane] + b[lane]);
    unsigned short x1 = f2bf(d1 * rstd * g[lane + 64] + b[lane + 64]);
    int b0 = (tkn * 256 + lane * 2) ^ ((tkn & 15) << 4);
    int b1 = (tkn * 256 + (lane + 64) * 2) ^ ((tkn & 15) << 4);
    *(unsigned short*)((char*)axn + b0) = x0;
    *(unsigned short*)((char*)axn + b1) = x1;
  }
  __syncthreads();
  // QKV: 24 col-tiles (3 mats x 8), 6 per wave
  int q4 = lane >> 4, m = lane & 15;
  bf16x8 a[4];
  #pragma unroll
  for (int ks = 0; ks < 4; ks++) {
    int boff = (m * 256 + ks * 64 + q4 * 16) ^ (m << 4);
    a[ks] = *(const bf16x8*)((char*)axn + boff);
  }
  int swbase = ((nv ^ 1) << 12) + i0;
  #pragma unroll
  for (int tt = 0; tt < 6; ++tt) {
    int gt = wave * 6 + tt;          // 0..23
    int mat = gt >> 3, ct = gt & 7;
    const unsigned short* bp = wt + mat * 16384 + (size_t)(ct * 16 + m) * C + q4 * 8;
    f32x4 acc = (f32x4){0.f, 0.f, 0.f, 0.f};
    #pragma unroll
    for (int ks = 0; ks < 4; ks++) {
      bf16x8 bfrag = *(const bf16x8*)(bp + ks * 32);
      acc = MFMA16(a[ks], bfrag, acc);
    }
    const float* B = (mat == 0) ? bq : ((mat == 1) ? bk : bv);
    float sc = (mat == 0) ? QSCALE : 1.0f;
    unsigned short* O = (mat == 0) ? qh : ((mat == 1) ? ksw : vsw);
    int base = (mat == 0) ? t0 : swbase;
    int col = ct * 16 + m;
    float bb = B[col];
    #pragma unroll
    for (int reg = 0; reg < 4; reg++) {
      int row = base + q4 * 4 + reg;
      O[(size_t)row * C + col] = f2h((acc[reg] + bb) * sc);
    }
  }
}

// ---------------- K3: fused gather-attention + proj + residual + LN2 + fc1 --------
// FINAL: best-known configuration (R11, 193.9 us total; K3 56-57 us). Lever
// inventory, all measured: deeper reg-ILP -> serialized (R1/R5/R6) or spilled
// (R7); sched_barrier pinning -> spill; global_load_lds gather -> 1 block/CU
// (R9, 116 us); 512-thread blocks -> regressed (R6); 2x grid -> regressed (R13).
// 4 tok/wave + 2x32 V reg-batches + launch_bounds(256,3) is the empirical optimum.
__global__ __launch_bounds__(256, 3) void k_attn_proj_fc1(
    const unsigned short* __restrict__ qh, const unsigned short* __restrict__ ksw,
    const unsigned short* __restrict__ vsw, const int* __restrict__ widx,
    const float* __restrict__ dprob, const float* __restrict__ kpe,
    const float* __restrict__ vpe, const float* __restrict__ rpe,
    const unsigned short* __restrict__ wt, const float* __restrict__ pb,
    const float* __restrict__ feat, float* __restrict__ xio,
    const float* __restrict__ g2, const float* __restrict__ b2,
    const float* __restrict__ f1b, unsigned short* __restrict__ y) {
  // 16 tokens x 128 ch bf16, XOR-swizzled: byte ^= (row&15)<<4.
  __shared__ unsigned short axn[16 * C];
  __shared__ float ps1[4][16];
  __shared__ float ps2[4][16];
  int lane = threadIdx.x & 63;
  int wave = threadIdx.x >> 6;
  int bid = blockIdx.x;
  int n = (bid >> 1) & 3;                       // view pair -> XCD locality
  int within = ((bid >> 3) << 1) | (bid & 1);   // 0..255
  int T0 = n * HW + within * 16;
  const unsigned short* Kb = ksw + (size_t)n * HW * C;
  const unsigned short* Vb = vsw + (size_t)n * HW * C;
  int gg = lane >> 3, s = lane & 7;
  half2v ones = {(_Float16)1.0f, (_Float16)1.0f};

  // ---- Phase A: attention, 4 tokens per wave, deep load ILP ----
  for (int tj = 0; tj < 4; ++tj) {
    int token = T0 + wave * 4 + tj;
    int myidx = widx[(size_t)token * D + lane];
    float mydp = dprob[(size_t)token * D + lane];
    // Q segment (f16): channels [s*16, s*16+16) as 8 half2
    half2v qreg[8];
    {
      const unsigned short* qp = qh + (size_t)token * C + s * 16;
      U4H qa, qb2;
      qa.v = *(const uint4*)(qp);
      qb2.v = *(const uint4*)(qp + 8);
      #pragma unroll
      for (int i = 0; i < 4; i++) { qreg[i] = qa.h[i]; qreg[4 + i] = qb2.h[i]; }
    }
    // issue ALL 16 K-row loads
    int rowv[8];
    #pragma unroll
    for (int pass = 0; pass < 8; ++pass)
      rowv[pass] = __shfl(myidx, pass * 8 + gg, 64);
    uint4 ka[8], kb[8];
    #pragma unroll
    for (int pass = 0; pass < 8; ++pass) {
      const unsigned short* kr = Kb + (size_t)rowv[pass] * C + s * 16;
      ka[pass] = *(const uint4*)(kr);
      kb[pass] = *(const uint4*)(kr + 8);
    }
    // issue V batch 0 (32 rows) - in flight across QmK+softmax
    unsigned vv0[32];
    #pragma unroll
    for (int j = 0; j < 32; j++) {
      int row = __builtin_amdgcn_readlane(myidx, j);
      vv0[j] = *(const unsigned*)(Vb + (size_t)row * C + lane * 2);
    }
    // qpe (VALU, overlaps load latency)
    float qpe = 0.f;
    #pragma unroll
    for (int i = 0; i < 8; i++) qpe = dot2h(qreg[i], ones, qpe);
    qpe += __shfl_xor(qpe, 1, 64);
    qpe += __shfl_xor(qpe, 2, 64);
    qpe += __shfl_xor(qpe, 4, 64);
    // QmK (consumes ka/kb; V batch 0 still in flight)
    float mycost = 0.f;
    #pragma unroll
    for (int pass = 0; pass < 8; ++pass) {
      U4H ua, ub;
      ua.v = ka[pass]; ub.v = kb[pass];
      float p = 0.f;
      #pragma unroll
      for (int i = 0; i < 4; i++) p = dot2h(ua.h[i], qreg[i], p);
      #pragma unroll
      for (int i = 0; i < 4; i++) p = dot2h(ub.h[i], qreg[4 + i], p);
      p += __shfl_xor(p, 1, 64);
      p += __shfl_xor(p, 2, 64);
      p += __shfl_xor(p, 4, 64);
      float t = __shfl(p, (lane & 7) << 3, 64);
      if (pass == gg) mycost = t;
    }
    mycost += qpe * kpe[lane] + rpe[lane];
    // softmax + renorm (VALU/shfl only; V batch 0 still in flight)
    float mx = mycost;
    for (int off = 32; off; off >>= 1) mx = fmaxf(mx, __shfl_xor(mx, off, 64));
    float e = __expf(mycost - mx);
    float ssum = e;
    for (int off = 32; off; off >>= 1) ssum += __shfl_xor(ssum, off, 64);
    float attn = (e / ssum) * mydp;
    float s2 = attn;
    for (int off = 32; off; off >>= 1) s2 += __shfl_xor(s2, off, 64);
    attn = (attn + EPS_R) / (s2 + EPS_R);
    float vpt = attn * vpe[lane];
    for (int off = 32; off; off >>= 1) vpt += __shfl_xor(vpt, off, 64);
    // issue V batch 1 (32 rows), then consume batch 0, then batch 1
    float o0 = vpt, o1 = vpt;
    unsigned att_u = __float_as_uint(attn);
    unsigned vv1[32];
    #pragma unroll
    for (int j = 0; j < 32; j++) {
      int row = __builtin_amdgcn_readlane(myidx, 32 + j);
      vv1[j] = *(const unsigned*)(Vb + (size_t)row * C + lane * 2);
    }
    #pragma unroll
    for (int j = 0; j < 32; j++) {
      float a = __uint_as_float(__builtin_amdgcn_readlane(att_u, j));
      U1H h; h.v = vv0[j];
      o0 += a * (float)h.h.x;   // v_fma_mix_f32
      o1 += a * (float)h.h.y;
    }
    #pragma unroll
    for (int j = 0; j < 32; j++) {
      float a = __uint_as_float(__builtin_amdgcn_readlane(att_u, 32 + j));
      U1H h; h.v = vv1[j];
      o0 += a * (float)h.h.x;
      o1 += a * (float)h.h.y;
    }
    unsigned pk = (unsigned)f2bf(o0) | ((unsigned)f2bf(o1) << 16);
    int row = wave * 4 + tj;
    int boff = (row * 256 + lane * 4) ^ ((row & 15) << 4);
    *(unsigned*)((char*)axn + boff) = pk;
  }
  __syncthreads();

  // ---- Phase B: proj GEMM (16 tok x 32 cols per wave) + residual + LN2 ----
  int q4 = lane >> 4, m = lane & 15;
  bf16x8 a[4];
  #pragma unroll
  for (int ks = 0; ks < 4; ks++) {
    int boff = (m * 256 + ks * 64 + q4 * 16) ^ (m << 4);
    a[ks] = *(const bf16x8*)((char*)axn + boff);
  }
  const unsigned short* Wp = wt + 3 * 16384;  // pwT
  f32x4 acc[2];
  #pragma unroll
  for (int nt = 0; nt < 2; nt++) acc[nt] = (f32x4){0.f, 0.f, 0.f, 0.f};
  #pragma unroll
  for (int nt = 0; nt < 2; nt++) {
    int colt = wave * 32 + nt * 16;
    const unsigned short* bp = Wp + (size_t)(colt + m) * C + q4 * 8;
    #pragma unroll
    for (int ks = 0; ks < 4; ks++) {
      bf16x8 bfrag = *(const bf16x8*)(bp + ks * 32);
      acc[nt] = MFMA16(a[ks], bfrag, acc[nt]);
    }
  }
  int ibase = (T0 & 4095) + q4 * 4;
  float s1[4] = {0.f, 0.f, 0.f, 0.f}, s2b[4] = {0.f, 0.f, 0.f, 0.f};
  #pragma unroll
  for (int nt = 0; nt < 2; nt++) {
    int col = wave * 32 + nt * 16 + m;
    float bb = pb[col];
    const float* fp = feat + ((size_t)n * C + col) * HW + ibase;
    #pragma unroll
    for (int reg = 0; reg < 4; reg++) {
      float v = acc[nt][reg] + bb + fp[reg];
      acc[nt][reg] = v;
      s1[reg] += v;
      s2b[reg] += v * v;
    }
  }
  #pragma unroll
  for (int reg = 0; reg < 4; reg++) {
    #pragma unroll
    for (int off = 1; off < 16; off <<= 1) {
      s1[reg] += __shfl_xor(s1[reg], off, 64);
      s2b[reg] += __shfl_xor(s2b[reg], off, 64);
    }
  }
  if (m == 0) {
    #pragma unroll
    for (int reg = 0; reg < 4; reg++) {
      ps1[wave][q4 * 4 + reg] = s1[reg];
      ps2[wave][q4 * 4 + reg] = s2b[reg];
    }
  }
  __syncthreads();
  float mean[4], rstd[4];
  #pragma unroll
  for (int reg = 0; reg < 4; reg++) {
    int row = q4 * 4 + reg;
    float t1 = ps1[0][row] + ps1[1][row] + ps1[2][row] + ps1[3][row];
    float t2 = ps2[0][row] + ps2[1][row] + ps2[2][row] + ps2[3][row];
    mean[reg] = t1 * (1.0f / 128.0f);
    float var = t2 * (1.0f / 128.0f) - mean[reg] * mean[reg];
    rstd[reg] = rsqrtf(var + LN_EPS);
  }
  #pragma unroll
  for (int nt = 0; nt < 2; nt++) {
    int col = wave * 32 + nt * 16 + m;
    float gc = g2[col], bc = b2[col];
    #pragma unroll
    for (int reg = 0; reg < 4; reg++) {
      int row = q4 * 4 + reg;
      float v = acc[nt][reg];
      xio[(size_t)(T0 + row) * C + col] = v;
      unsigned short xv = f2bf((v - mean[reg]) * rstd[reg] * gc + bc);
      int boff = (row * 256 + col * 2) ^ ((row & 15) << 4);
      *(unsigned short*)((char*)axn + boff) = xv;
    }
  }
  __syncthreads();

  // ---- Phase C: fc1 GEMM (16 tok x 64 cols per wave) + GELU -> y ----
  bf16x8 af[4];
  #pragma unroll
  for (int ks = 0; ks < 4; ks++) {
    int boff = (m * 256 + ks * 64 + q4 * 16) ^ (m << 4);
    af[ks] = *(const bf16x8*)((char*)axn + boff);
  }
  const unsigned short* Wf = wt + 65536;  // f1wT [256][128]
  #pragma unroll
  for (int nt = 0; nt < 4; nt++) {
    int colt = wave * 64 + nt * 16;
    const unsigned short* bp = Wf + (size_t)(colt + m) * C + q4 * 8;
    f32x4 acc2 = (f32x4){0.f, 0.f, 0.f, 0.f};
    #pragma unroll
    for (int ks = 0; ks < 4; ks++) {
      bf16x8 bfrag = *(const bf16x8*)(bp + ks * 32);
      acc2 = MFMA16(af[ks], bfrag, acc2);
    }
    int col = colt + m;
    float bb = f1b[col];
    #pragma unroll
    for (int reg = 0; reg < 4; reg++) {
      int row = T0 + q4 * 4 + reg;
      y[(size_t)row * HID + col] = f2bf(gelu_exact(acc2[reg] + bb));
    }
  }
}

// ---------------- K4: depthwise 5x5 conv + GELU; writes ysum = y + yc -------------
__global__ __launch_bounds__(256) void k_dwconv(const unsigned short* __restrict__ y,
    const float* __restrict__ w, const float* __restrict__ bias,
    unsigned short* __restrict__ ysum) {
  __shared__ float tile[8][401];   // [channel][spatial 20x20], odd stride
  __shared__ float wl[8][25];
  __shared__ float bl[8];
  __shared__ unsigned short outl[256][8];  // 16x16 spatial x 8 ch staging
  int bid = blockIdx.x;
  int tile_id = bid & 15;
  int cb = (bid >> 4) & 31;
  int n = bid >> 9;
  int ty = (tile_id >> 2) * 16, tx = (tile_id & 3) * 16;
  int ch0 = cb * 8;
  int tid = threadIdx.x;
  if (tid < 200) wl[tid / 25][tid % 25] = w[(size_t)(ch0 + tid / 25) * 25 + tid % 25];
  if (tid < 8) bl[tid] = bias[ch0 + tid];
  const unsigned short* yb = y + (size_t)n * HW * HID;
  for (int p = tid; p < 400; p += 256) {
    int py = p / 20, px = p % 20;
    int gy = ty + py - 2, gx = tx + px - 2;
    uint4 v = make_uint4(0u, 0u, 0u, 0u);
    if (gy >= 0 && gy < 64 && gx >= 0 && gx < 64)
      v = *(const uint4*)(yb + (size_t)(gy * 64 + gx) * HID + ch0);
    tile[0][p] = bflo(v.x); tile[1][p] = bfhi(v.x);
    tile[2][p] = bflo(v.y); tile[3][p] = bfhi(v.y);
    tile[4][p] = bflo(v.z); tile[5][p] = bfhi(v.z);
    tile[6][p] = bflo(v.w); tile[7][p] = bfhi(v.w);
  }
  __syncthreads();
  int cc = tid & 7;
  int xx = (tid >> 3) & 15;
  int yg = tid >> 7;
  float wreg[25];
  #pragma unroll
  for (int k = 0; k < 25; k++) wreg[k] = wl[cc][k];
  float bb = bl[cc];
  float win[12][5];
  #pragma unroll
  for (int r = 0; r < 12; r++)
    #pragma unroll
    for (int dx = 0; dx < 5; dx++)
      win[r][dx] = tile[cc][(yg * 8 + r) * 20 + xx + dx];
  #pragma unroll
  for (int j = 0; j < 8; ++j) {
    float acc = 0.f;
    #pragma unroll
    for (int dy = 0; dy < 5; ++dy)
      #pragma unroll
      for (int dx = 0; dx < 5; ++dx)
        acc += wreg[dy * 5 + dx] * win[j + dy][dx];
    float o = win[j + 2][2] + gelu_exact(acc + bb);
    int yy = yg * 8 + j;
    outl[yy * 16 + xx][cc] = f2bf(o);
  }
  __syncthreads();
  {
    int p = tid;
    int yy = p >> 4, xx2 = p & 15;
    uint4 val = *(const uint4*)outl[p];
    *(uint4*)(ysum + (size_t)(n * HW + (ty + yy) * 64 + tx + xx2) * HID + ch0) = val;
  }
}

// ---------------- K5: fc2 GEMM (MFMA, col-split x4) on ysum + residual ------------
__global__ __launch_bounds__(256) void k_fc2(const unsigned short* __restrict__ ysum,
    const unsigned short* __restrict__ wt, const float* __restrict__ f2b,
    const float* __restrict__ xio, float* __restrict__ outp) {
  int w = threadIdx.x >> 6, lane = threadIdx.x & 63;
  int q4 = lane >> 4, m = lane & 15;
  int t0 = blockIdx.x * 64 + w * 16;
  int quarter = blockIdx.y;
  const unsigned short* Wt = wt + 98304;  // f2wT [128][256]
  const unsigned short* ap = ysum + (size_t)(t0 + m) * HID + q4 * 8;
  bf16x8 a[8];
  #pragma unroll
  for (int ks = 0; ks < 8; ks++) a[ks] = *(const bf16x8*)(ap + ks * 32);
  f32x4 acc[2];
  #pragma unroll
  for (int nt = 0; nt < 2; nt++) acc[nt] = (f32x4){0.f, 0.f, 0.f, 0.f};
  #pragma unroll
  for (int nt = 0; nt < 2; nt++) {
    const unsigned short* bp = Wt + (size_t)(quarter * 32 + nt * 16 + m) * HID + q4 * 8;
    #pragma unroll
    for (int ks = 0; ks < 8; ks++) {
      bf16x8 bfrag = *(const bf16x8*)(bp + ks * 32);
      acc[nt] = MFMA16(a[ks], bfrag, acc[nt]);
    }
  }
  #pragma unroll
  for (int nt = 0; nt < 2; nt++) {
    int col = quarter * 32 + nt * 16 + m;
    float bb = f2b[col];
    #pragma unroll
    for (int reg = 0; reg < 4; reg++) {
      int row = t0 + q4 * 4 + reg;
      outp[(size_t)row * C + col] = acc[nt][reg] + bb + xio[(size_t)row * C + col];
    }
  }
}

extern "C" void kernel_launch(void* const* d_in, const int* in_sizes, int n_in,
                              void* d_out, int out_size, void* d_ws, size_t ws_size,
                              hipStream_t stream) {
  (void)in_sizes; (void)n_in; (void)out_size; (void)ws_size;
  const float* feat  = (const float*)d_in[0];
  const int*   widx  = (const int*)d_in[1];
  const float* dprob = (const float*)d_in[2];
  const float* ln1g  = (const float*)d_in[3];
  const float* ln1b  = (const float*)d_in[4];
  const float* wq    = (const float*)d_in[5];
  const float* bq    = (const float*)d_in[6];
  const float* wk    = (const float*)d_in[7];
  const float* bk    = (const float*)d_in[8];
  const float* wv    = (const float*)d_in[9];
  const float* bv    = (const float*)d_in[10];
  const float* kpe   = (const float*)d_in[11];
  const float* vpe   = (const float*)d_in[12];
  const float* rpe   = (const float*)d_in[13];
  const float* pw    = (const float*)d_in[14];
  const float* pb    = (const float*)d_in[15];
  const float* ln2g  = (const float*)d_in[16];
  const float* ln2b  = (const float*)d_in[17];
  const float* f1w   = (const float*)d_in[18];
  const float* f1b   = (const float*)d_in[19];
  const float* dww   = (const float*)d_in[20];
  const float* dwb   = (const float*)d_in[21];
  const float* f2w   = (const float*)d_in[22];
  const float* f2b   = (const float*)d_in[23];

  float* ws = (float*)d_ws;
  const size_t M2 = (size_t)TOK * C;  // 2,097,152 floats (8 MB)
  float* xio = ws;                                                   // fp32 residual stream
  unsigned short* qhb   = (unsigned short*)(ws + M2);                // f16 q (scaled)
  unsigned short* ksb   = (unsigned short*)(ws + 2 * M2);            // f16 K (swapped)
  unsigned short* vsb   = (unsigned short*)(ws + 2 * M2 + M2 / 2);   // f16 V (swapped)
  unsigned short* yb    = (unsigned short*)(ws + 3 * M2);            // bf16 fc1 out (2*M2 ush)
  unsigned short* ysumb = (unsigned short*)(ws + 4 * M2);            // bf16 y+yc (2*M2 ush)
  unsigned short* wtb   = (unsigned short*)(ws + 5 * M2);            // bf16 weights (131072 ush)

  k_prep   <<<512, 256, 0, stream>>>(wq, wk, wv, pw, f1w, f2w, wtb);
  k_ln1qkv <<<1024, 256, 0, stream>>>(feat, ln1g, ln1b, wtb, bq, bk, bv, qhb, ksb, vsb);
  k_attn_proj_fc1<<<1024, 256, 0, stream>>>(qhb, ksb, vsb, widx, dprob, kpe, vpe,
                                            rpe, wtb, pb, feat, xio, ln2g, ln2b,
                                            f1b, yb);
  k_dwconv <<<2048, 256, 0, stream>>>(yb, dww, dwb, ysumb);
  k_fc2    <<<dim3(TOK / 64, 4), 256, 0, stream>>>(ysumb, wtb, f2b, xio, (float*)d_out);
}